// Round 11
// baseline (237.494 us; speedup 1.0000x reference)
//
#include <hip/hip_runtime.h>
#include <hip/hip_bf16.h>
#include <cstdint>

// Problem constants (from reference): B=4, T=2048, D=512, FF=2048, E=8, K=2
#define NTOK   8192      // B*T
#define DDIM   512
#define FDIM   2048
#define NEXP   8
#define NSLOT  16384     // 2*NTOK assignments (top-2, always exactly 2 per token)
#define MAXT256 72       // sum_e ceil(cnt_e/256) <= 16384/256 + 8

typedef __bf16 bf16;
typedef __bf16 bf16x8 __attribute__((ext_vector_type(8)));
typedef float  f32x4  __attribute__((ext_vector_type(4)));

typedef uint32_t __attribute__((address_space(1))) gu32;
typedef uint32_t __attribute__((address_space(3))) lu32;

// async global->LDS, 16B per lane; LDS dest must be wave-uniform base (+lane*16 implicit)
__device__ __forceinline__ void gload16(const void* g, void* l) {
    __builtin_amdgcn_global_load_lds((const gu32*)(uintptr_t)g,
                                     (lu32*)(uintptr_t)l, 16, 0, 0);
}

// ---------------- gating: logits -> softmax -> top2 -> weights; also x->bf16 ----
__global__ __launch_bounds__(256)
void gating_kernel(const float* __restrict__ x, const float* __restrict__ Wg,
                   const float* __restrict__ bg, bf16* __restrict__ xb,
                   int* __restrict__ top_idx, float* __restrict__ top_w,
                   int* __restrict__ counts)
{
    __shared__ int cnt_s[NEXP];
    if (threadIdx.x < NEXP) cnt_s[threadIdx.x] = 0;
    __syncthreads();

    const int w = threadIdx.x >> 6;
    const int l = threadIdx.x & 63;
    const int gw = blockIdx.x * 4 + w;   // 1024 blocks * 4 waves = 4096 waves

    for (int n = gw; n < NTOK; n += 4096) {
        const float4* xp = (const float4*)(x + (size_t)n * DDIM + l * 8);
        float4 x0 = xp[0], x1 = xp[1];
        float xf[8] = {x0.x, x0.y, x0.z, x0.w, x1.x, x1.y, x1.z, x1.w};

        bf16x8 xv;
#pragma unroll
        for (int i = 0; i < 8; ++i) xv[i] = (bf16)xf[i];
        *(bf16x8*)(xb + (size_t)n * DDIM + l * 8) = xv;

        float acc[8] = {0.f,0.f,0.f,0.f,0.f,0.f,0.f,0.f};
#pragma unroll
        for (int i = 0; i < 8; ++i) {
            const float4* wp = (const float4*)(Wg + (size_t)(l * 8 + i) * NEXP);
            float4 wa = wp[0], wb = wp[1];
            acc[0] += xf[i] * wa.x; acc[1] += xf[i] * wa.y;
            acc[2] += xf[i] * wa.z; acc[3] += xf[i] * wa.w;
            acc[4] += xf[i] * wb.x; acc[5] += xf[i] * wb.y;
            acc[6] += xf[i] * wb.z; acc[7] += xf[i] * wb.w;
        }
#pragma unroll
        for (int m = 32; m >= 1; m >>= 1)
#pragma unroll
            for (int e = 0; e < 8; ++e)
                acc[e] += __shfl_xor(acc[e], m);

        if (l == 0) {
            float logit[8];
#pragma unroll
            for (int e = 0; e < 8; ++e) logit[e] = acc[e] + bg[e];
            float mx = logit[0];
#pragma unroll
            for (int e = 1; e < 8; ++e) mx = fmaxf(mx, logit[e]);
            float g[8], s = 0.f;
#pragma unroll
            for (int e = 0; e < 8; ++e) { g[e] = expf(logit[e] - mx); s += g[e]; }
            float inv = 1.f / s;
#pragma unroll
            for (int e = 0; e < 8; ++e) g[e] *= inv;
            // top-2, ties -> lower index first (matches lax.top_k)
            int e0 = 0;
#pragma unroll
            for (int e = 1; e < 8; ++e) if (g[e] > g[e0]) e0 = e;
            int e1 = (e0 == 0) ? 1 : 0;
#pragma unroll
            for (int e = 0; e < 8; ++e) if (e != e0 && e != e1 && g[e] > g[e1]) e1 = e;
            float denom = g[e0] + g[e1] + 0.01f;
            top_idx[n * 2 + 0] = e0;
            top_idx[n * 2 + 1] = e1;
            top_w[n * 2 + 0] = g[e0] / denom;
            top_w[n * 2 + 1] = g[e1] / denom;
            atomicAdd(&cnt_s[e0], 1);
            atomicAdd(&cnt_s[e1], 1);
        }
    }
    __syncthreads();
    if (threadIdx.x < NEXP) atomicAdd(&counts[threadIdx.x], cnt_s[threadIdx.x]);
}

// ---------------- scan: offsets, 256-granule tile map, zero cursors -------------
__global__ void scan_kernel(const int* __restrict__ counts, int* __restrict__ offsets,
                            int* __restrict__ tmap_e, int* __restrict__ tmap_rt,
                            int* __restrict__ ntiles, int* __restrict__ cursors)
{
    if (threadIdx.x == 0) {
        int off = 0;
        for (int e = 0; e < NEXP; ++e) { offsets[e] = off; off += counts[e]; cursors[e] = 0; }
        offsets[NEXP] = off;
        int t = 0;
        for (int e = 0; e < NEXP; ++e) {
            int nt = (counts[e] + 255) >> 8;
            for (int rt = 0; rt < nt; ++rt) { tmap_e[t] = e; tmap_rt[t] = rt; ++t; }
        }
        *ntiles = t;
    }
}

// ---------------- scatter: block-aggregated cursor reservation ------------------
__global__ __launch_bounds__(256)
void scatter_kernel(const int* __restrict__ top_idx, const float* __restrict__ top_w,
                    const int* __restrict__ offsets, int* __restrict__ cursors,
                    int* __restrict__ slot_tok, float* __restrict__ slot_w,
                    int* __restrict__ pos)
{
    __shared__ int lcnt[NEXP];
    __shared__ int lbase[NEXP];
    const int t = threadIdx.x;
    if (t < NEXP) lcnt[t] = 0;
    __syncthreads();
    const int n = blockIdx.x * 256 + t;   // NTOK = 32*256 exactly
    const int e0 = top_idx[n * 2 + 0];
    const int e1 = top_idx[n * 2 + 1];
    const int r0 = atomicAdd(&lcnt[e0], 1);
    const int r1 = atomicAdd(&lcnt[e1], 1);
    __syncthreads();
    if (t < NEXP) lbase[t] = atomicAdd(&cursors[t], lcnt[t]);
    __syncthreads();
    const int s0 = offsets[e0] + lbase[e0] + r0;
    const int s1 = offsets[e1] + lbase[e1] + r1;
    slot_tok[s0] = n; slot_w[s0] = top_w[n * 2 + 0]; pos[n * 2 + 0] = s0;
    slot_tok[s1] = n; slot_w[s1] = top_w[n * 2 + 1]; pos[n * 2 + 1] = s1;
}

// ---------------- fp32 [E][R][C] -> bf16 [E][C][R] transpose+convert ------------
__global__ __launch_bounds__(256)
void transpose_cvt(const float* __restrict__ src, bf16* __restrict__ dst, int R, int C)
{
    __shared__ bf16 tile[64][72];   // 72 = 16B-aligned row stride, rotates banks
    const size_t eo = (size_t)blockIdx.z * R * C;
    src += eo; dst += eo;
    const int c0 = blockIdx.x * 64, r0 = blockIdx.y * 64;
    const int tq = (threadIdx.x & 15) * 4;   // col quad within 64
    const int tr = threadIdx.x >> 4;         // 16 rows per pass
#pragma unroll
    for (int j = 0; j < 4; ++j) {
        const int r = tr + j * 16;
        float4 v = *(const float4*)(src + (size_t)(r0 + r) * C + c0 + tq);
        tile[tq + 0][r] = (bf16)v.x;
        tile[tq + 1][r] = (bf16)v.y;
        tile[tq + 2][r] = (bf16)v.z;
        tile[tq + 3][r] = (bf16)v.w;
    }
    __syncthreads();
    const int x8 = (threadIdx.x & 7) * 8;    // 8 bf16 = 16B per store
    const int cr = threadIdx.x >> 3;         // 32 rows per pass
#pragma unroll
    for (int j = 0; j < 2; ++j) {
        const int c = cr + j * 32;
        *(bf16x8*)(dst + (size_t)(c0 + c) * R + r0 + x8) = *(const bf16x8*)&tile[c][x8];
    }
}

// ------ grouped GEMM, 256x256 tile, 8-phase-style ring pipeline ------------------
// 8 waves (2M x 4N), wave tile 128x64 (acc[8][4]); BK=32, 4-buffer LDS ring
// (4 x (A 16KB + B 16KB) = 128 KB -> 1 block/CU, by design like m201/HK).
// Per K-tile: 2 phases {ds_read frags; issue 2 prefetch gloads; barrier;
// setprio(1) 16 MFMA setprio(0); barrier}; boundary s_waitcnt vmcnt(8)
// (tail 8->4->0) -- loads issued 3 K-tiles (6 phases) before their wait.
// T2 swizzle: LDS slot p at row r holds global 16B-slot p ^ ((r>>1)&3);
// staging pre-swizzles the GLOBAL source (linear LDS dest), reads XOR back.
// FIRST:  A = xb (via slot_tok), B = w1t, Out = Hg (bias+relu), SK=1
// !FIRST: A = Hg,                B = w2t, Out = Yg bf16 partial K-slices
template<int KD, int ND, bool FIRST, int SK>
__global__ __launch_bounds__(512, 2)
void moe_gemm(const bf16* __restrict__ Adata, const bf16* __restrict__ Bt,
              const float* __restrict__ bias, bf16* __restrict__ Out,
              const int* __restrict__ slot_tok, const int* __restrict__ offsets,
              const int* __restrict__ tmap_e, const int* __restrict__ tmap_rt,
              const int* __restrict__ ntiles)
{
    constexpr int NX  = ND / 256;          // N-tiles: 8 (GEMM1) or 2 (GEMM2)
    constexpr int XD  = NX * SK;           // grid.x: 8 (G1), 8 (G2 SK4) or 4 (SK2)
    constexpr int NWG = XD * MAXT256;      // 576 / 576 / 288 — all % 8 == 0
    constexpr int Q   = NWG / 8;
    constexpr int NT  = KD / 32;           // K-tiles per slice: 16 or 32

    const int orig = blockIdx.y * XD + blockIdx.x;       // HW dispatch order
    const int work = (orig & 7) * Q + (orig >> 3);       // bijective XCD chunking
    const int wy   = work / XD;                          // row-tile
    const int rem  = work - wy * XD;
    const int wx   = rem % NX;                           // N-tile (fastest: shares A)
    const int ks   = rem / NX;                           // K-slice
    if (wy >= *ntiles) return;

    const int e    = tmap_e[wy];
    const int rt   = tmap_rt[wy];
    const int row0 = offsets[e] + rt * 256;
    const int rowEnd = offsets[e + 1];
    const int nb   = wx * 256;
    const int kbase = ks * KD;

    // ring of 4 K-tile buffers: A[4][256][32], B[4][256][32] bf16 = 128 KB
    __shared__ __align__(16) bf16 As[4 * 256 * 32];
    __shared__ __align__(16) bf16 Bs[4 * 256 * 32];

    const int tid = threadIdx.x;
    const int w = tid >> 6, l = tid & 63;  // 8 waves
    const int wm = w >> 2, wn = w & 3;     // 2x4 wave grid, 128x64 per wave
    const int lr = l & 15;
    const int sl = l >> 4;                 // k quarter 0..3 (16B slots)
    const int fo = (lr >> 1) & 3;          // read-side swizzle term

    // staging: per matrix, per load j in {0,1}: rows j*128 + (tid>>2),
    // phys slot tid&3; source k-slot pre-swizzled = (tid&3) ^ ((row>>1)&3)
    const int srow_sub = tid >> 2;                       // 0..127
    const int ksrc = (((tid & 3) ^ ((tid >> 3) & 3)) * 8);

    const bf16* aSrcJ[2];
    const bf16* bSrcJ[2];
#pragma unroll
    for (int j = 0; j < 2; ++j) {
        const int r = j * 128 + srow_sub;
        int sr = row0 + r; if (sr >= NSLOT) sr = NSLOT - 1;
        if (FIRST) aSrcJ[j] = Adata + (size_t)slot_tok[sr] * (KD * SK) + kbase + ksrc;
        else       aSrcJ[j] = Adata + (size_t)sr * (KD * SK) + kbase + ksrc;
        bSrcJ[j] = Bt + ((size_t)e * ND + nb + r) * (KD * SK) + kbase + ksrc;
    }

    f32x4 acc[8][4] = {};

    auto STAGE_A = [&](int kt) {
        const int buf = kt & 3;
        gload16(aSrcJ[0] + kt * 32, As + buf * 8192 + w * 512);
        gload16(aSrcJ[1] + kt * 32, As + buf * 8192 + 4096 + w * 512);
    };
    auto STAGE_B = [&](int kt) {
        const int buf = kt & 3;
        gload16(bSrcJ[0] + kt * 32, Bs + buf * 8192 + w * 512);
        gload16(bSrcJ[1] + kt * 32, Bs + buf * 8192 + 4096 + w * 512);
    };

    auto KTILE = [&](int kt, bool doStage) {
        const bf16* ab = As + (kt & 3) * 8192;
        const bf16* bb = Bs + (kt & 3) * 8192;
        const int ko = (sl ^ fo) * 8;
        // ---- phase A: mi 0..3 ----
        bf16x8 aF[4], bF[4];
#pragma unroll
        for (int i = 0; i < 4; ++i)
            aF[i] = *(const bf16x8*)(ab + (wm * 128 + i * 16 + lr) * 32 + ko);
#pragma unroll
        for (int j = 0; j < 4; ++j)
            bF[j] = *(const bf16x8*)(bb + (wn * 64 + j * 16 + lr) * 32 + ko);
        if (doStage) STAGE_A(kt + 3);
        __builtin_amdgcn_s_barrier();
        __builtin_amdgcn_sched_barrier(0);
        __builtin_amdgcn_s_setprio(1);
#pragma unroll
        for (int i = 0; i < 4; ++i)
#pragma unroll
            for (int j = 0; j < 4; ++j)
                acc[i][j] = __builtin_amdgcn_mfma_f32_16x16x32_bf16(aF[i], bF[j], acc[i][j], 0, 0, 0);
        __builtin_amdgcn_s_setprio(0);
        __builtin_amdgcn_s_barrier();
        __builtin_amdgcn_sched_barrier(0);
        // ---- phase B: mi 4..7 (bF reused from registers) ----
        bf16x8 aG[4];
#pragma unroll
        for (int i = 0; i < 4; ++i)
            aG[i] = *(const bf16x8*)(ab + (wm * 128 + (i + 4) * 16 + lr) * 32 + ko);
        if (doStage) STAGE_B(kt + 3);
        __builtin_amdgcn_s_barrier();
        __builtin_amdgcn_sched_barrier(0);
        __builtin_amdgcn_s_setprio(1);
#pragma unroll
        for (int i = 0; i < 4; ++i)
#pragma unroll
            for (int j = 0; j < 4; ++j)
                acc[i + 4][j] = __builtin_amdgcn_mfma_f32_16x16x32_bf16(aG[i], bF[j], acc[i + 4][j], 0, 0, 0);
        __builtin_amdgcn_s_setprio(0);
        __builtin_amdgcn_s_barrier();
        __builtin_amdgcn_sched_barrier(0);
    };

    // prologue: stage K-tiles 0,1,2 (12 loads/wave in flight)
    STAGE_A(0); STAGE_B(0);
    STAGE_A(1); STAGE_B(1);
    STAGE_A(2); STAGE_B(2);
    __builtin_amdgcn_sched_barrier(0);

    // main: boundary wait leaves the 2 younger K-tiles' 8 loads in flight
    for (int kt = 0; kt < NT - 3; ++kt) {
        asm volatile("s_waitcnt vmcnt(8)" ::: "memory");
        __builtin_amdgcn_sched_barrier(0);
        __builtin_amdgcn_s_barrier();
        __builtin_amdgcn_sched_barrier(0);
        KTILE(kt, true);
    }
    // tail: 3 K-tiles, no staging; waits 8 -> 4 -> 0
    asm volatile("s_waitcnt vmcnt(8)" ::: "memory");
    __builtin_amdgcn_sched_barrier(0);
    __builtin_amdgcn_s_barrier();
    __builtin_amdgcn_sched_barrier(0);
    KTILE(NT - 3, false);
    asm volatile("s_waitcnt vmcnt(4)" ::: "memory");
    __builtin_amdgcn_sched_barrier(0);
    __builtin_amdgcn_s_barrier();
    __builtin_amdgcn_sched_barrier(0);
    KTILE(NT - 2, false);
    asm volatile("s_waitcnt vmcnt(0)" ::: "memory");
    __builtin_amdgcn_sched_barrier(0);
    __builtin_amdgcn_s_barrier();
    __builtin_amdgcn_sched_barrier(0);
    KTILE(NT - 1, false);

    const int rowW = row0 + wm * 128;
    const int colW = nb + wn * 64;
    bf16* outBase = Out + (size_t)ks * NSLOT * ND;
#pragma unroll
    for (int mi = 0; mi < 8; ++mi) {
#pragma unroll
        for (int nj = 0; nj < 4; ++nj) {
#pragma unroll
            for (int r = 0; r < 4; ++r) {
                int row = rowW + mi * 16 + sl * 4 + r;
                int col = colW + nj * 16 + lr;
                if (row < rowEnd) {
                    float v = acc[mi][nj][r];
                    if (FIRST)        v = fmaxf(v + bias[e * ND + col], 0.f);
                    else if (ks == 0) v = v + bias[e * ND + col];
                    outBase[(size_t)row * ND + col] = (bf16)v;
                }
            }
        }
    }
}

// ---------------- combine: out[n] = sum_k w_k * sum_slices Y[slot_k] -------------
__global__ __launch_bounds__(256)
void combine_kernel(const bf16* __restrict__ Yg, const int* __restrict__ pos,
                    const float* __restrict__ slot_w, float* __restrict__ out,
                    int nsl)
{
    const int idx = blockIdx.x * 256 + threadIdx.x;  // over NTOK*DDIM/8
    const int n  = idx >> 6;                          // DDIM/8 = 64
    const int d8 = (idx & 63) * 8;
    const int s0 = pos[n * 2 + 0], s1 = pos[n * 2 + 1];
    const float w0 = slot_w[s0], w1 = slot_w[s1];
    float oa[8] = {0,0,0,0,0,0,0,0};
    float ob[8] = {0,0,0,0,0,0,0,0};
    for (int sl = 0; sl < nsl; ++sl) {
        const bf16* y = Yg + (size_t)sl * NSLOT * DDIM;
        bf16x8 a = *(const bf16x8*)(y + (size_t)s0 * DDIM + d8);
        bf16x8 b = *(const bf16x8*)(y + (size_t)s1 * DDIM + d8);
#pragma unroll
        for (int j = 0; j < 8; ++j) { oa[j] += (float)a[j]; ob[j] += (float)b[j]; }
    }
    float o[8];
#pragma unroll
    for (int j = 0; j < 8; ++j) o[j] = w0 * oa[j] + w1 * ob[j];
    float* op = out + (size_t)n * DDIM + d8;
    *(float4*)(op + 0) = make_float4(o[0], o[1], o[2], o[3]);
    *(float4*)(op + 4) = make_float4(o[4], o[5], o[6], o[7]);
}

extern "C" void kernel_launch(void* const* d_in, const int* in_sizes, int n_in,
                              void* d_out, int out_size, void* d_ws, size_t ws_size,
                              hipStream_t stream)
{
    (void)in_sizes; (void)n_in;
    const float* x  = (const float*)d_in[0];
    const float* Wg = (const float*)d_in[1];
    const float* bg = (const float*)d_in[2];
    const float* W1 = (const float*)d_in[3];
    const float* b1 = (const float*)d_in[4];
    const float* W2 = (const float*)d_in[5];
    const float* b2 = (const float*)d_in[6];
    float* out = (float*)d_out;

    uint8_t* ws = (uint8_t*)d_ws;
    size_t off = 0;
    auto alloc = [&](size_t bytes) -> void* {
        void* p = ws + off;
        off = (off + bytes + 255) & ~(size_t)255;
        return p;
    };
    bf16*  xb      = (bf16*)alloc((size_t)NTOK * DDIM * 2);
    bf16*  w1t     = (bf16*)alloc((size_t)NEXP * FDIM * DDIM * 2);  // [E][FF][D]
    bf16*  w2t     = (bf16*)alloc((size_t)NEXP * DDIM * FDIM * 2);  // [E][D][FF]
    bf16*  Hg      = (bf16*)alloc((size_t)NSLOT * FDIM * 2);
    int*   counts  = (int*)alloc(NEXP * 4);
    int*   cursors = (int*)alloc(NEXP * 4);
    int*   offsets = (int*)alloc((NEXP + 1) * 4);
    int*   ntiles  = (int*)alloc(4);
    int*   tmap_e  = (int*)alloc(MAXT256 * 4);
    int*   tmap_rt = (int*)alloc(MAXT256 * 4);
    int*   top_idx = (int*)alloc((size_t)NTOK * 2 * 4);
    float* top_w   = (float*)alloc((size_t)NTOK * 2 * 4);
    int*   pos     = (int*)alloc((size_t)NTOK * 2 * 4);
    int*   slot_tok= (int*)alloc((size_t)NSLOT * 4);
    float* slot_w  = (float*)alloc((size_t)NSLOT * 4);

    // Yg last: prefer split-K=4 (4 bf16 slices); fall back to 2 if ws is tight.
    const size_t yslice = (size_t)NSLOT * DDIM * 2;
    int sk = 4;
    if (off + 4 * yslice + 256 > ws_size) sk = 2;
    bf16* Yg = (bf16*)alloc((size_t)sk * yslice);

    if (ws_size < off) {
        // workspace too small even for SK=2: loud failure signature (out = 0)
        hipMemsetAsync(d_out, 0, (size_t)out_size * 4, stream);
        return;
    }

    hipMemsetAsync(counts, 0, NEXP * 4, stream);

    gating_kernel<<<1024, 256, 0, stream>>>(x, Wg, bg, xb, top_idx, top_w, counts);
    scan_kernel<<<1, 64, 0, stream>>>(counts, offsets, tmap_e, tmap_rt, ntiles, cursors);
    scatter_kernel<<<NTOK / 256, 256, 0, stream>>>(top_idx, top_w, offsets, cursors,
                                                   slot_tok, slot_w, pos);
    transpose_cvt<<<dim3(FDIM / 64, DDIM / 64, NEXP), 256, 0, stream>>>(W1, w1t, DDIM, FDIM);
    transpose_cvt<<<dim3(DDIM / 64, FDIM / 64, NEXP), 256, 0, stream>>>(W2, w2t, FDIM, DDIM);

    moe_gemm<DDIM, FDIM, true, 1><<<dim3(FDIM / 256, MAXT256), 512, 0, stream>>>(
        xb, w1t, b1, Hg, slot_tok, offsets, tmap_e, tmap_rt, ntiles);

    if (sk == 4) {
        moe_gemm<FDIM / 4, DDIM, false, 4><<<dim3((DDIM / 256) * 4, MAXT256), 512, 0, stream>>>(
            Hg, w2t, b2, Yg, slot_tok, offsets, tmap_e, tmap_rt, ntiles);
    } else {
        moe_gemm<FDIM / 2, DDIM, false, 2><<<dim3((DDIM / 256) * 2, MAXT256), 512, 0, stream>>>(
            Hg, w2t, b2, Yg, slot_tok, offsets, tmap_e, tmap_rt, ntiles);
    }

    combine_kernel<<<(NTOK * DDIM / 8) / 256, 256, 0, stream>>>(Yg, pos, slot_w, out, sk);
}

// Round 12
// 178.357 us; speedup vs baseline: 1.3316x; 1.3316x over previous
//
#include <hip/hip_runtime.h>
#include <hip/hip_bf16.h>
#include <cstdint>

// Problem constants (from reference): B=4, T=2048, D=512, FF=2048, E=8, K=2
#define NTOK   8192      // B*T
#define DDIM   512
#define FDIM   2048
#define NEXP   8
#define NSLOT  16384     // 2*NTOK assignments (top-2, always exactly 2 per token)
#define MAXTILES 136     // sum_e ceil(cnt_e/128) <= 16384/128 + 8

typedef __bf16 bf16;
typedef __bf16 bf16x8 __attribute__((ext_vector_type(8)));
typedef float  f32x4  __attribute__((ext_vector_type(4)));

typedef uint32_t __attribute__((address_space(1))) gu32;
typedef uint32_t __attribute__((address_space(3))) lu32;

// async global->LDS, 16B per lane; LDS dest must be wave-uniform base (+lane*16 implicit)
__device__ __forceinline__ void gload16(const void* g, void* l) {
    __builtin_amdgcn_global_load_lds((const gu32*)(uintptr_t)g,
                                     (lu32*)(uintptr_t)l, 16, 0, 0);
}

// ---------------- gating: logits -> softmax -> top2 -> weights; also x->bf16 ----
__global__ __launch_bounds__(256)
void gating_kernel(const float* __restrict__ x, const float* __restrict__ Wg,
                   const float* __restrict__ bg, bf16* __restrict__ xb,
                   int* __restrict__ top_idx, float* __restrict__ top_w,
                   int* __restrict__ counts)
{
    __shared__ int cnt_s[NEXP];
    if (threadIdx.x < NEXP) cnt_s[threadIdx.x] = 0;
    __syncthreads();

    const int w = threadIdx.x >> 6;
    const int l = threadIdx.x & 63;
    const int gw = blockIdx.x * 4 + w;   // 1024 blocks * 4 waves = 4096 waves

    for (int n = gw; n < NTOK; n += 4096) {
        const float4* xp = (const float4*)(x + (size_t)n * DDIM + l * 8);
        float4 x0 = xp[0], x1 = xp[1];
        float xf[8] = {x0.x, x0.y, x0.z, x0.w, x1.x, x1.y, x1.z, x1.w};

        bf16x8 xv;
#pragma unroll
        for (int i = 0; i < 8; ++i) xv[i] = (bf16)xf[i];
        *(bf16x8*)(xb + (size_t)n * DDIM + l * 8) = xv;

        float acc[8] = {0.f,0.f,0.f,0.f,0.f,0.f,0.f,0.f};
#pragma unroll
        for (int i = 0; i < 8; ++i) {
            const float4* wp = (const float4*)(Wg + (size_t)(l * 8 + i) * NEXP);
            float4 wa = wp[0], wb = wp[1];
            acc[0] += xf[i] * wa.x; acc[1] += xf[i] * wa.y;
            acc[2] += xf[i] * wa.z; acc[3] += xf[i] * wa.w;
            acc[4] += xf[i] * wb.x; acc[5] += xf[i] * wb.y;
            acc[6] += xf[i] * wb.z; acc[7] += xf[i] * wb.w;
        }
#pragma unroll
        for (int m = 32; m >= 1; m >>= 1)
#pragma unroll
            for (int e = 0; e < 8; ++e)
                acc[e] += __shfl_xor(acc[e], m);

        if (l == 0) {
            float logit[8];
#pragma unroll
            for (int e = 0; e < 8; ++e) logit[e] = acc[e] + bg[e];
            float mx = logit[0];
#pragma unroll
            for (int e = 1; e < 8; ++e) mx = fmaxf(mx, logit[e]);
            float g[8], s = 0.f;
#pragma unroll
            for (int e = 0; e < 8; ++e) { g[e] = expf(logit[e] - mx); s += g[e]; }
            float inv = 1.f / s;
#pragma unroll
            for (int e = 0; e < 8; ++e) g[e] *= inv;
            // top-2, ties -> lower index first (matches lax.top_k)
            int e0 = 0;
#pragma unroll
            for (int e = 1; e < 8; ++e) if (g[e] > g[e0]) e0 = e;
            int e1 = (e0 == 0) ? 1 : 0;
#pragma unroll
            for (int e = 0; e < 8; ++e) if (e != e0 && e != e1 && g[e] > g[e1]) e1 = e;
            float denom = g[e0] + g[e1] + 0.01f;
            top_idx[n * 2 + 0] = e0;
            top_idx[n * 2 + 1] = e1;
            top_w[n * 2 + 0] = g[e0] / denom;
            top_w[n * 2 + 1] = g[e1] / denom;
            atomicAdd(&cnt_s[e0], 1);
            atomicAdd(&cnt_s[e1], 1);
        }
    }
    __syncthreads();
    if (threadIdx.x < NEXP) atomicAdd(&counts[threadIdx.x], cnt_s[threadIdx.x]);
}

// ---------------- scan: offsets, tile map, zero cursors (single thread, tiny) ----
__global__ void scan_kernel(const int* __restrict__ counts, int* __restrict__ offsets,
                            int* __restrict__ tmap_e, int* __restrict__ tmap_rt,
                            int* __restrict__ ntiles, int* __restrict__ cursors)
{
    if (threadIdx.x == 0) {
        int off = 0;
        for (int e = 0; e < NEXP; ++e) { offsets[e] = off; off += counts[e]; cursors[e] = 0; }
        offsets[NEXP] = off;
        int t = 0;
        for (int e = 0; e < NEXP; ++e) {
            int nt = (counts[e] + 127) >> 7;
            for (int rt = 0; rt < nt; ++rt) { tmap_e[t] = e; tmap_rt[t] = rt; ++t; }
        }
        *ntiles = t;
    }
}

// ---------------- scatter: block-aggregated cursor reservation ------------------
__global__ __launch_bounds__(256)
void scatter_kernel(const int* __restrict__ top_idx, const float* __restrict__ top_w,
                    const int* __restrict__ offsets, int* __restrict__ cursors,
                    int* __restrict__ slot_tok, float* __restrict__ slot_w,
                    int* __restrict__ pos)
{
    __shared__ int lcnt[NEXP];
    __shared__ int lbase[NEXP];
    const int t = threadIdx.x;
    if (t < NEXP) lcnt[t] = 0;
    __syncthreads();
    const int n = blockIdx.x * 256 + t;   // NTOK = 32*256 exactly
    const int e0 = top_idx[n * 2 + 0];
    const int e1 = top_idx[n * 2 + 1];
    const int r0 = atomicAdd(&lcnt[e0], 1);
    const int r1 = atomicAdd(&lcnt[e1], 1);
    __syncthreads();
    if (t < NEXP) lbase[t] = atomicAdd(&cursors[t], lcnt[t]);
    __syncthreads();
    const int s0 = offsets[e0] + lbase[e0] + r0;
    const int s1 = offsets[e1] + lbase[e1] + r1;
    slot_tok[s0] = n; slot_w[s0] = top_w[n * 2 + 0]; pos[n * 2 + 0] = s0;
    slot_tok[s1] = n; slot_w[s1] = top_w[n * 2 + 1]; pos[n * 2 + 1] = s1;
}

// ---------------- fp32 [E][R][C] -> bf16 [E][C][R] transpose+convert ------------
__global__ __launch_bounds__(256)
void transpose_cvt(const float* __restrict__ src, bf16* __restrict__ dst, int R, int C)
{
    __shared__ bf16 tile[64][72];   // 72 = 16B-aligned row stride, rotates banks
    const size_t eo = (size_t)blockIdx.z * R * C;
    src += eo; dst += eo;
    const int c0 = blockIdx.x * 64, r0 = blockIdx.y * 64;
    const int tq = (threadIdx.x & 15) * 4;   // col quad within 64
    const int tr = threadIdx.x >> 4;         // 16 rows per pass
#pragma unroll
    for (int j = 0; j < 4; ++j) {
        const int r = tr + j * 16;
        float4 v = *(const float4*)(src + (size_t)(r0 + r) * C + c0 + tq);
        tile[tq + 0][r] = (bf16)v.x;
        tile[tq + 1][r] = (bf16)v.y;
        tile[tq + 2][r] = (bf16)v.z;
        tile[tq + 3][r] = (bf16)v.w;
    }
    __syncthreads();
    const int x8 = (threadIdx.x & 7) * 8;    // 8 bf16 = 16B per store
    const int cr = threadIdx.x >> 3;         // 32 rows per pass
#pragma unroll
    for (int j = 0; j < 2; ++j) {
        const int c = cr + j * 32;
        *(bf16x8*)(dst + (size_t)(c0 + c) * R + r0 + x8) = *(const bf16x8*)&tile[c][x8];
    }
}

// ---------------- grouped GEMM: R9 structure + T2 XOR slot swizzle --------------
// (Exact R9 geometry — best measured 178.97us — plus the bank-conflict fix.)
// C[slot, n] = A[slot, :KD] * B_e[n, :KD]^T
// FIRST:  A = xb (via slot_tok indirection), B = w1t, Out = Hg (bias+relu+bf16)
// !FIRST: A = Hg (direct slot rows),         B = w2t, Out = Yg (bias, bf16)
// 512 threads = 8 waves (wave grid 4x2, each wave 32x64 output).
// LDS: 2 tile-buffers x (4KB A + 4KB B) x ... = 32KB -> 5 blocks/CU.
// T2 swizzle (rule #21, both-sides): each 64B LDS row = 4 x 16B slots.
//   stage: lane l's linear LDS dest (slot l&3, row w*16+(l>>2)) is filled from
//          GLOBAL k-slot (l&3)^((l>>3)&3)  [(row>>1)&3 == (l>>3)&3]
//   read:  global k-slot sl=(l>>4) at row R lives at phys slot sl^((R>>1)&3);
//          (R>>1)&3 == (lr>>1)&3 for all frag rows (mi*16, wn*64 are 0 mod 8).
//   -> every byte of a frag region read exactly once per wave: 0 excess cycles.
template<int KD, int ND, bool FIRST>
__global__ __launch_bounds__(512)
void moe_gemm(const bf16* __restrict__ Adata, const bf16* __restrict__ Bt,
              const float* __restrict__ bias, bf16* __restrict__ Out,
              const int* __restrict__ slot_tok, const int* __restrict__ offsets,
              const int* __restrict__ tmap_e, const int* __restrict__ tmap_rt,
              const int* __restrict__ ntiles)
{
    constexpr int NX  = ND / 128;          // N-tiles: 16 (GEMM1) or 4 (GEMM2)
    constexpr int NWG = NX * MAXTILES;     // 2176 / 544 — both % 8 == 0
    constexpr int Q   = NWG / 8;
    constexpr int NT  = KD / 32;           // K-tiles: 16 (GEMM1) or 64 (GEMM2)

    const int orig = blockIdx.y * NX + blockIdx.x;       // HW dispatch order
    const int work = (orig & 7) * Q + (orig >> 3);       // bijective XCD chunking
    const int wy   = work / NX;                          // row-tile
    const int wx   = work - wy * NX;                     // N-tile (fastest: shares A)
    if (wy >= *ntiles) return;

    const int e    = tmap_e[wy];
    const int rt   = tmap_rt[wy];
    const int row0 = offsets[e] + rt * 128;
    const int rowEnd = offsets[e + 1];
    const int nb   = wx * 128;

    // double-buffered LDS: [2] x 128x32 bf16 for A and B  (32KB total)
    __shared__ __align__(16) bf16 As[2 * 128 * 32];
    __shared__ __align__(16) bf16 Bs[2 * 128 * 32];

    const int t = threadIdx.x;
    const int w = t >> 6, l = t & 63;      // 8 waves
    const int wm = w >> 1, wn = w & 1;     // 4x2 wave grid, 32x64 per wave

    // staging: wave w stages rows w*16 .. w*16+15 of A-tile and B-tile (1KB each)
    const int rA   = w * 16 + (l >> 2);
    // T2: pre-swizzled global k-slot for this lane's linear LDS dest
    const int colb = (((l & 3) ^ ((l >> 3) & 3)) * 8);

    int srow = row0 + rA; if (srow >= NSLOT) srow = NSLOT - 1;
    const bf16* aSrc;
    if (FIRST) aSrc = Adata + (size_t)slot_tok[srow] * KD + colb;
    else       aSrc = Adata + (size_t)srow * KD + colb;
    const bf16* bSrc = Bt + ((size_t)e * ND + nb + rA) * KD + colb;

    const int offW = w * 512;   // elem offset of this wave's 1KB chunk

    f32x4 acc[2][4] = {};
    const int lr = l & 15;
    // T2 read-side: phys slot = (l>>4) ^ ((lr>>1)&3)
    const int lks = (((l >> 4) ^ ((lr >> 1) & 3)) * 8);

    auto STAGE = [&](int buf, int k0) {
        gload16(aSrc + k0, As + buf * 4096 + offW);
        gload16(bSrc + k0, Bs + buf * 4096 + offW);
    };
    auto COMPUTE = [&](int buf) {
        const bf16* ab = As + buf * 4096;
        const bf16* bb = Bs + buf * 4096;
        bf16x8 aF[2], bF[4];
#pragma unroll
        for (int mi = 0; mi < 2; ++mi)
            aF[mi] = *(const bf16x8*)(ab + (wm * 32 + mi * 16 + lr) * 32 + lks);
#pragma unroll
        for (int nj = 0; nj < 4; ++nj)
            bF[nj] = *(const bf16x8*)(bb + (wn * 64 + nj * 16 + lr) * 32 + lks);
#pragma unroll
        for (int mi = 0; mi < 2; ++mi)
#pragma unroll
            for (int nj = 0; nj < 4; ++nj)
                acc[mi][nj] = __builtin_amdgcn_mfma_f32_16x16x32_bf16(
                    aF[mi], bF[nj], acc[mi][nj], 0, 0, 0);
    };

    // prologue: 2 tiles in flight (4 loads/wave)
    STAGE(0, 0);
    STAGE(1, 32);
    __builtin_amdgcn_sched_barrier(0);

    for (int t2 = 0; t2 < NT - 2; ++t2) {
        // wait for tile t2's 2 loads (next tile's 2 stay in flight)
        asm volatile("s_waitcnt vmcnt(2)" ::: "memory");
        __builtin_amdgcn_sched_barrier(0);
        __builtin_amdgcn_s_barrier();
        __builtin_amdgcn_sched_barrier(0);
        COMPUTE(t2 & 1);
        __builtin_amdgcn_s_barrier();            // all waves done reading buf
        __builtin_amdgcn_sched_barrier(0);
        STAGE(t2 & 1, (t2 + 2) * 32);
        __builtin_amdgcn_sched_barrier(0);
    }
    // tail: two tiles remain; vmcnt 2 -> 0
    asm volatile("s_waitcnt vmcnt(2)" ::: "memory");
    __builtin_amdgcn_sched_barrier(0);
    __builtin_amdgcn_s_barrier();
    __builtin_amdgcn_sched_barrier(0);
    COMPUTE(NT & 1);            // (NT-2) & 1
    __builtin_amdgcn_s_barrier();
    __builtin_amdgcn_sched_barrier(0);
    asm volatile("s_waitcnt vmcnt(0)" ::: "memory");
    __builtin_amdgcn_sched_barrier(0);
    __builtin_amdgcn_s_barrier();
    __builtin_amdgcn_sched_barrier(0);
    COMPUTE((NT - 1) & 1);

    const int rowW = row0 + wm * 32;
    const int colW = nb + wn * 64;
#pragma unroll
    for (int mi = 0; mi < 2; ++mi) {
#pragma unroll
        for (int nj = 0; nj < 4; ++nj) {
#pragma unroll
            for (int r = 0; r < 4; ++r) {
                int row = rowW + mi * 16 + (l >> 4) * 4 + r;
                int col = colW + nj * 16 + lr;
                if (row < rowEnd) {
                    float v = acc[mi][nj][r] + bias[e * ND + col];
                    if (FIRST) v = fmaxf(v, 0.f);
                    Out[(size_t)row * ND + col] = (bf16)v;
                }
            }
        }
    }
}

// ---------------- combine: out[n] = w0*Y[slot0] + w1*Y[slot1] (bf16 Y) ----------
__global__ __launch_bounds__(256)
void combine_kernel(const bf16* __restrict__ Yg, const int* __restrict__ pos,
                    const float* __restrict__ slot_w, float* __restrict__ out)
{
    const int idx = blockIdx.x * 256 + threadIdx.x;  // over NTOK*DDIM/8
    const int n  = idx >> 6;                          // DDIM/8 = 64
    const int d8 = (idx & 63) * 8;
    const int s0 = pos[n * 2 + 0], s1 = pos[n * 2 + 1];
    const float w0 = slot_w[s0], w1 = slot_w[s1];
    bf16x8 a = *(const bf16x8*)(Yg + (size_t)s0 * DDIM + d8);
    bf16x8 b = *(const bf16x8*)(Yg + (size_t)s1 * DDIM + d8);
    float o[8];
#pragma unroll
    for (int j = 0; j < 8; ++j)
        o[j] = w0 * (float)a[j] + w1 * (float)b[j];
    float* op = out + (size_t)n * DDIM + d8;
    *(float4*)(op + 0) = make_float4(o[0], o[1], o[2], o[3]);
    *(float4*)(op + 4) = make_float4(o[4], o[5], o[6], o[7]);
}

extern "C" void kernel_launch(void* const* d_in, const int* in_sizes, int n_in,
                              void* d_out, int out_size, void* d_ws, size_t ws_size,
                              hipStream_t stream)
{
    (void)in_sizes; (void)n_in;
    const float* x  = (const float*)d_in[0];
    const float* Wg = (const float*)d_in[1];
    const float* bg = (const float*)d_in[2];
    const float* W1 = (const float*)d_in[3];
    const float* b1 = (const float*)d_in[4];
    const float* W2 = (const float*)d_in[5];
    const float* b2 = (const float*)d_in[6];
    float* out = (float*)d_out;

    uint8_t* ws = (uint8_t*)d_ws;
    size_t off = 0;
    auto alloc = [&](size_t bytes) -> void* {
        void* p = ws + off;
        off = (off + bytes + 255) & ~(size_t)255;
        return p;
    };
    bf16*  xb      = (bf16*)alloc((size_t)NTOK * DDIM * 2);
    bf16*  w1t     = (bf16*)alloc((size_t)NEXP * FDIM * DDIM * 2);  // [E][FF][D]
    bf16*  w2t     = (bf16*)alloc((size_t)NEXP * DDIM * FDIM * 2);  // [E][D][FF]
    bf16*  Hg      = (bf16*)alloc((size_t)NSLOT * FDIM * 2);
    bf16*  Yg      = (bf16*)alloc((size_t)NSLOT * DDIM * 2);
    int*   counts  = (int*)alloc(NEXP * 4);
    int*   cursors = (int*)alloc(NEXP * 4);
    int*   offsets = (int*)alloc((NEXP + 1) * 4);
    int*   ntiles  = (int*)alloc(4);
    int*   tmap_e  = (int*)alloc(MAXTILES * 4);
    int*   tmap_rt = (int*)alloc(MAXTILES * 4);
    int*   top_idx = (int*)alloc((size_t)NTOK * 2 * 4);
    float* top_w   = (float*)alloc((size_t)NTOK * 2 * 4);
    int*   pos     = (int*)alloc((size_t)NTOK * 2 * 4);
    int*   slot_tok= (int*)alloc((size_t)NSLOT * 4);
    float* slot_w  = (float*)alloc((size_t)NSLOT * 4);

    if (ws_size < off) {
        // workspace too small: distinguishable failure signature (out = 0)
        hipMemsetAsync(d_out, 0, (size_t)out_size * 4, stream);
        return;
    }

    hipMemsetAsync(counts, 0, NEXP * 4, stream);

    gating_kernel<<<1024, 256, 0, stream>>>(x, Wg, bg, xb, top_idx, top_w, counts);
    scan_kernel<<<1, 64, 0, stream>>>(counts, offsets, tmap_e, tmap_rt, ntiles, cursors);
    scatter_kernel<<<NTOK / 256, 256, 0, stream>>>(top_idx, top_w, offsets, cursors,
                                                   slot_tok, slot_w, pos);
    transpose_cvt<<<dim3(FDIM / 64, DDIM / 64, NEXP), 256, 0, stream>>>(W1, w1t, DDIM, FDIM);
    transpose_cvt<<<dim3(DDIM / 64, FDIM / 64, NEXP), 256, 0, stream>>>(W2, w2t, FDIM, DDIM);

    moe_gemm<DDIM, FDIM, true><<<dim3(FDIM / 128, MAXTILES), 512, 0, stream>>>(
        xb, w1t, b1, Hg, slot_tok, offsets, tmap_e, tmap_rt, ntiles);
    moe_gemm<FDIM, DDIM, false><<<dim3(DDIM / 128, MAXTILES), 512, 0, stream>>>(
        Hg, w2t, b2, Yg, slot_tok, offsets, tmap_e, tmap_rt, ntiles);

    combine_kernel<<<(NTOK * DDIM / 8) / 256, 256, 0, stream>>>(Yg, pos, slot_w, out);
}

// Round 13
// 176.055 us; speedup vs baseline: 1.3490x; 1.0131x over previous
//
#include <hip/hip_runtime.h>
#include <hip/hip_bf16.h>
#include <cstdint>

// Problem constants (from reference): B=4, T=2048, D=512, FF=2048, E=8, K=2
#define NTOK   8192      // B*T
#define DDIM   512
#define FDIM   2048
#define NEXP   8
#define NSLOT  16384     // 2*NTOK assignments (top-2, always exactly 2 per token)
#define MAXTILES 136     // sum_e ceil(cnt_e/128) <= 16384/128 + 8

typedef __bf16 bf16;
typedef __bf16 bf16x8 __attribute__((ext_vector_type(8)));
typedef float  f32x4  __attribute__((ext_vector_type(4)));

typedef uint32_t __attribute__((address_space(1))) gu32;
typedef uint32_t __attribute__((address_space(3))) lu32;

// async global->LDS, 16B per lane; LDS dest must be wave-uniform base (+lane*16 implicit)
__device__ __forceinline__ void gload16(const void* g, void* l) {
    __builtin_amdgcn_global_load_lds((const gu32*)(uintptr_t)g,
                                     (lu32*)(uintptr_t)l, 16, 0, 0);
}

// ---------------- gating: logits -> softmax -> top2 -> weights; also x->bf16 ----
__global__ __launch_bounds__(256)
void gating_kernel(const float* __restrict__ x, const float* __restrict__ Wg,
                   const float* __restrict__ bg, bf16* __restrict__ xb,
                   int* __restrict__ top_idx, float* __restrict__ top_w,
                   int* __restrict__ counts)
{
    __shared__ int cnt_s[NEXP];
    if (threadIdx.x < NEXP) cnt_s[threadIdx.x] = 0;
    __syncthreads();

    const int w = threadIdx.x >> 6;
    const int l = threadIdx.x & 63;
    const int gw = blockIdx.x * 4 + w;   // 1024 blocks * 4 waves = 4096 waves

    for (int n = gw; n < NTOK; n += 4096) {
        const float4* xp = (const float4*)(x + (size_t)n * DDIM + l * 8);
        float4 x0 = xp[0], x1 = xp[1];
        float xf[8] = {x0.x, x0.y, x0.z, x0.w, x1.x, x1.y, x1.z, x1.w};

        bf16x8 xv;
#pragma unroll
        for (int i = 0; i < 8; ++i) xv[i] = (bf16)xf[i];
        *(bf16x8*)(xb + (size_t)n * DDIM + l * 8) = xv;

        float acc[8] = {0.f,0.f,0.f,0.f,0.f,0.f,0.f,0.f};
#pragma unroll
        for (int i = 0; i < 8; ++i) {
            const float4* wp = (const float4*)(Wg + (size_t)(l * 8 + i) * NEXP);
            float4 wa = wp[0], wb = wp[1];
            acc[0] += xf[i] * wa.x; acc[1] += xf[i] * wa.y;
            acc[2] += xf[i] * wa.z; acc[3] += xf[i] * wa.w;
            acc[4] += xf[i] * wb.x; acc[5] += xf[i] * wb.y;
            acc[6] += xf[i] * wb.z; acc[7] += xf[i] * wb.w;
        }
#pragma unroll
        for (int m = 32; m >= 1; m >>= 1)
#pragma unroll
            for (int e = 0; e < 8; ++e)
                acc[e] += __shfl_xor(acc[e], m);

        if (l == 0) {
            float logit[8];
#pragma unroll
            for (int e = 0; e < 8; ++e) logit[e] = acc[e] + bg[e];
            float mx = logit[0];
#pragma unroll
            for (int e = 1; e < 8; ++e) mx = fmaxf(mx, logit[e]);
            float g[8], s = 0.f;
#pragma unroll
            for (int e = 0; e < 8; ++e) { g[e] = expf(logit[e] - mx); s += g[e]; }
            float inv = 1.f / s;
#pragma unroll
            for (int e = 0; e < 8; ++e) g[e] *= inv;
            // top-2, ties -> lower index first (matches lax.top_k)
            int e0 = 0;
#pragma unroll
            for (int e = 1; e < 8; ++e) if (g[e] > g[e0]) e0 = e;
            int e1 = (e0 == 0) ? 1 : 0;
#pragma unroll
            for (int e = 0; e < 8; ++e) if (e != e0 && e != e1 && g[e] > g[e1]) e1 = e;
            float denom = g[e0] + g[e1] + 0.01f;
            top_idx[n * 2 + 0] = e0;
            top_idx[n * 2 + 1] = e1;
            top_w[n * 2 + 0] = g[e0] / denom;
            top_w[n * 2 + 1] = g[e1] / denom;
            atomicAdd(&cnt_s[e0], 1);
            atomicAdd(&cnt_s[e1], 1);
        }
    }
    __syncthreads();
    if (threadIdx.x < NEXP) atomicAdd(&counts[threadIdx.x], cnt_s[threadIdx.x]);
}

// ---------------- scan: offsets, tile map, zero cursors (single thread, tiny) ----
__global__ void scan_kernel(const int* __restrict__ counts, int* __restrict__ offsets,
                            int* __restrict__ tmap_e, int* __restrict__ tmap_rt,
                            int* __restrict__ ntiles, int* __restrict__ cursors)
{
    if (threadIdx.x == 0) {
        int off = 0;
        for (int e = 0; e < NEXP; ++e) { offsets[e] = off; off += counts[e]; cursors[e] = 0; }
        offsets[NEXP] = off;
        int t = 0;
        for (int e = 0; e < NEXP; ++e) {
            int nt = (counts[e] + 127) >> 7;
            for (int rt = 0; rt < nt; ++rt) { tmap_e[t] = e; tmap_rt[t] = rt; ++t; }
        }
        *ntiles = t;
    }
}

// ---------------- scatter: block-aggregated cursor reservation ------------------
__global__ __launch_bounds__(256)
void scatter_kernel(const int* __restrict__ top_idx, const float* __restrict__ top_w,
                    const int* __restrict__ offsets, int* __restrict__ cursors,
                    int* __restrict__ slot_tok, float* __restrict__ slot_w,
                    int* __restrict__ pos)
{
    __shared__ int lcnt[NEXP];
    __shared__ int lbase[NEXP];
    const int t = threadIdx.x;
    if (t < NEXP) lcnt[t] = 0;
    __syncthreads();
    const int n = blockIdx.x * 256 + t;   // NTOK = 32*256 exactly
    const int e0 = top_idx[n * 2 + 0];
    const int e1 = top_idx[n * 2 + 1];
    const int r0 = atomicAdd(&lcnt[e0], 1);
    const int r1 = atomicAdd(&lcnt[e1], 1);
    __syncthreads();
    if (t < NEXP) lbase[t] = atomicAdd(&cursors[t], lcnt[t]);
    __syncthreads();
    const int s0 = offsets[e0] + lbase[e0] + r0;
    const int s1 = offsets[e1] + lbase[e1] + r1;
    slot_tok[s0] = n; slot_w[s0] = top_w[n * 2 + 0]; pos[n * 2 + 0] = s0;
    slot_tok[s1] = n; slot_w[s1] = top_w[n * 2 + 1]; pos[n * 2 + 1] = s1;
}

// ---------------- fp32 [E][R][C] -> bf16 [E][C][R] transpose+convert ------------
__global__ __launch_bounds__(256)
void transpose_cvt(const float* __restrict__ src, bf16* __restrict__ dst, int R, int C)
{
    __shared__ bf16 tile[64][72];   // 72 = 16B-aligned row stride, rotates banks
    const size_t eo = (size_t)blockIdx.z * R * C;
    src += eo; dst += eo;
    const int c0 = blockIdx.x * 64, r0 = blockIdx.y * 64;
    const int tq = (threadIdx.x & 15) * 4;   // col quad within 64
    const int tr = threadIdx.x >> 4;         // 16 rows per pass
#pragma unroll
    for (int j = 0; j < 4; ++j) {
        const int r = tr + j * 16;
        float4 v = *(const float4*)(src + (size_t)(r0 + r) * C + c0 + tq);
        tile[tq + 0][r] = (bf16)v.x;
        tile[tq + 1][r] = (bf16)v.y;
        tile[tq + 2][r] = (bf16)v.z;
        tile[tq + 3][r] = (bf16)v.w;
    }
    __syncthreads();
    const int x8 = (threadIdx.x & 7) * 8;    // 8 bf16 = 16B per store
    const int cr = threadIdx.x >> 3;         // 32 rows per pass
#pragma unroll
    for (int j = 0; j < 2; ++j) {
        const int c = cr + j * 32;
        *(bf16x8*)(dst + (size_t)(c0 + c) * R + r0 + x8) = *(const bf16x8*)&tile[c][x8];
    }
}

// ---------------- grouped GEMM: R12 geometry, m248-recipe 1-barrier loop --------
// C[slot, n] = A[slot, :KD] * B_e[n, :KD]^T
// FIRST:  A = xb (via slot_tok indirection), B = w1t, Out = Hg (bias+relu+bf16)
// !FIRST: A = Hg (direct slot rows),         B = w2t, Out = Yg (bias, bf16)
// 512 threads = 8 waves (4x2 wave grid, 32x64 per wave); 32KB dbuf -> 5 blocks/CU.
// K-loop = T3 "minimum 2-phase" recipe (m248): issue next-tile STAGE at TOP of
// the iteration, compute current, ONE __syncthreads at the bottom (compiler
// emits the vmcnt/lgkmcnt drain there). No inline asm, no sched_barrier —
// compiler schedules ds_read||gload||MFMA freely (m141: pinning costs ~40%).
// WAR safety with one barrier: iter t reads buf and stages buf^1; the bottom
// barrier follows all reads of buf, and buf is only overwritten in iter t+1
// (issued after every wave passed that barrier).
// T2 swizzle kept (conflicts = 0, verified R12): stage-side pre-swizzled global
// k-slot (l&3)^((l>>3)&3) with linear LDS dest; read-side phys slot
// (l>>4)^((lr>>1)&3).
template<int KD, int ND, bool FIRST>
__global__ __launch_bounds__(512)
void moe_gemm(const bf16* __restrict__ Adata, const bf16* __restrict__ Bt,
              const float* __restrict__ bias, bf16* __restrict__ Out,
              const int* __restrict__ slot_tok, const int* __restrict__ offsets,
              const int* __restrict__ tmap_e, const int* __restrict__ tmap_rt,
              const int* __restrict__ ntiles)
{
    constexpr int NX  = ND / 128;          // N-tiles: 16 (GEMM1) or 4 (GEMM2)
    constexpr int NWG = NX * MAXTILES;     // 2176 / 544 — both % 8 == 0
    constexpr int Q   = NWG / 8;
    constexpr int NT  = KD / 32;           // K-tiles: 16 (GEMM1) or 64 (GEMM2)

    const int orig = blockIdx.y * NX + blockIdx.x;       // HW dispatch order
    const int work = (orig & 7) * Q + (orig >> 3);       // bijective XCD chunking
    const int wy   = work / NX;                          // row-tile
    const int wx   = work - wy * NX;                     // N-tile (fastest: shares A)
    if (wy >= *ntiles) return;

    const int e    = tmap_e[wy];
    const int rt   = tmap_rt[wy];
    const int row0 = offsets[e] + rt * 128;
    const int rowEnd = offsets[e + 1];
    const int nb   = wx * 128;

    // double-buffered LDS: [2] x 128x32 bf16 for A and B  (32KB total)
    __shared__ __align__(16) bf16 As[2 * 128 * 32];
    __shared__ __align__(16) bf16 Bs[2 * 128 * 32];

    const int t = threadIdx.x;
    const int w = t >> 6, l = t & 63;      // 8 waves
    const int wm = w >> 1, wn = w & 1;     // 4x2 wave grid, 32x64 per wave

    // staging: wave w stages rows w*16 .. w*16+15 of A-tile and B-tile (1KB each)
    const int rA   = w * 16 + (l >> 2);
    // T2: pre-swizzled global k-slot for this lane's linear LDS dest
    const int colb = (((l & 3) ^ ((l >> 3) & 3)) * 8);

    int srow = row0 + rA; if (srow >= NSLOT) srow = NSLOT - 1;
    const bf16* aSrc;
    if (FIRST) aSrc = Adata + (size_t)slot_tok[srow] * KD + colb;
    else       aSrc = Adata + (size_t)srow * KD + colb;
    const bf16* bSrc = Bt + ((size_t)e * ND + nb + rA) * KD + colb;

    const int offW = w * 512;   // elem offset of this wave's 1KB chunk

    f32x4 acc[2][4] = {};
    const int lr = l & 15;
    // T2 read-side: phys slot = (l>>4) ^ ((lr>>1)&3)
    const int lks = (((l >> 4) ^ ((lr >> 1) & 3)) * 8);

    auto STAGE = [&](int buf, int k0) {
        gload16(aSrc + k0, As + buf * 4096 + offW);
        gload16(bSrc + k0, Bs + buf * 4096 + offW);
    };
    auto COMPUTE = [&](int buf) {
        const bf16* ab = As + buf * 4096;
        const bf16* bb = Bs + buf * 4096;
        bf16x8 aF[2], bF[4];
#pragma unroll
        for (int mi = 0; mi < 2; ++mi)
            aF[mi] = *(const bf16x8*)(ab + (wm * 32 + mi * 16 + lr) * 32 + lks);
#pragma unroll
        for (int nj = 0; nj < 4; ++nj)
            bF[nj] = *(const bf16x8*)(bb + (wn * 64 + nj * 16 + lr) * 32 + lks);
#pragma unroll
        for (int mi = 0; mi < 2; ++mi)
#pragma unroll
            for (int nj = 0; nj < 4; ++nj)
                acc[mi][nj] = __builtin_amdgcn_mfma_f32_16x16x32_bf16(
                    aF[mi], bF[nj], acc[mi][nj], 0, 0, 0);
    };

    // prologue: tile 0 staged and drained (compiler emits waits at the barrier)
    STAGE(0, 0);
    __syncthreads();

    int buf = 0;
    for (int t2 = 0; t2 < NT - 1; ++t2) {
        STAGE(buf ^ 1, (t2 + 1) * 32);   // issue next tile's loads first
        COMPUTE(buf);                     // ds_read + MFMA on current tile
        __syncthreads();                  // one barrier: drains loads, WAR-safe
        buf ^= 1;
    }
    COMPUTE(buf);                         // last tile (already drained)

    const int rowW = row0 + wm * 32;
    const int colW = nb + wn * 64;
#pragma unroll
    for (int mi = 0; mi < 2; ++mi) {
#pragma unroll
        for (int nj = 0; nj < 4; ++nj) {
#pragma unroll
            for (int r = 0; r < 4; ++r) {
                int row = rowW + mi * 16 + (l >> 4) * 4 + r;
                int col = colW + nj * 16 + lr;
                if (row < rowEnd) {
                    float v = acc[mi][nj][r] + bias[e * ND + col];
                    if (FIRST) v = fmaxf(v, 0.f);
                    Out[(size_t)row * ND + col] = (bf16)v;
                }
            }
        }
    }
}

// ---------------- combine: out[n] = w0*Y[slot0] + w1*Y[slot1] (bf16 Y) ----------
__global__ __launch_bounds__(256)
void combine_kernel(const bf16* __restrict__ Yg, const int* __restrict__ pos,
                    const float* __restrict__ slot_w, float* __restrict__ out)
{
    const int idx = blockIdx.x * 256 + threadIdx.x;  // over NTOK*DDIM/8
    const int n  = idx >> 6;                          // DDIM/8 = 64
    const int d8 = (idx & 63) * 8;
    const int s0 = pos[n * 2 + 0], s1 = pos[n * 2 + 1];
    const float w0 = slot_w[s0], w1 = slot_w[s1];
    bf16x8 a = *(const bf16x8*)(Yg + (size_t)s0 * DDIM + d8);
    bf16x8 b = *(const bf16x8*)(Yg + (size_t)s1 * DDIM + d8);
    float o[8];
#pragma unroll
    for (int j = 0; j < 8; ++j)
        o[j] = w0 * (float)a[j] + w1 * (float)b[j];
    float* op = out + (size_t)n * DDIM + d8;
    *(float4*)(op + 0) = make_float4(o[0], o[1], o[2], o[3]);
    *(float4*)(op + 4) = make_float4(o[4], o[5], o[6], o[7]);
}

extern "C" void kernel_launch(void* const* d_in, const int* in_sizes, int n_in,
                              void* d_out, int out_size, void* d_ws, size_t ws_size,
                              hipStream_t stream)
{
    (void)in_sizes; (void)n_in;
    const float* x  = (const float*)d_in[0];
    const float* Wg = (const float*)d_in[1];
    const float* bg = (const float*)d_in[2];
    const float* W1 = (const float*)d_in[3];
    const float* b1 = (const float*)d_in[4];
    const float* W2 = (const float*)d_in[5];
    const float* b2 = (const float*)d_in[6];
    float* out = (float*)d_out;

    uint8_t* ws = (uint8_t*)d_ws;
    size_t off = 0;
    auto alloc = [&](size_t bytes) -> void* {
        void* p = ws + off;
        off = (off + bytes + 255) & ~(size_t)255;
        return p;
    };
    bf16*  xb      = (bf16*)alloc((size_t)NTOK * DDIM * 2);
    bf16*  w1t     = (bf16*)alloc((size_t)NEXP * FDIM * DDIM * 2);  // [E][FF][D]
    bf16*  w2t     = (bf16*)alloc((size_t)NEXP * DDIM * FDIM * 2);  // [E][D][FF]
    bf16*  Hg      = (bf16*)alloc((size_t)NSLOT * FDIM * 2);
    bf16*  Yg      = (bf16*)alloc((size_t)NSLOT * DDIM * 2);
    int*   counts  = (int*)alloc(NEXP * 4);
    int*   cursors = (int*)alloc(NEXP * 4);
    int*   offsets = (int*)alloc((NEXP + 1) * 4);
    int*   ntiles  = (int*)alloc(4);
    int*   tmap_e  = (int*)alloc(MAXTILES * 4);
    int*   tmap_rt = (int*)alloc(MAXTILES * 4);
    int*   top_idx = (int*)alloc((size_t)NTOK * 2 * 4);
    float* top_w   = (float*)alloc((size_t)NTOK * 2 * 4);
    int*   pos     = (int*)alloc((size_t)NTOK * 2 * 4);
    int*   slot_tok= (int*)alloc((size_t)NSLOT * 4);
    float* slot_w  = (float*)alloc((size_t)NSLOT * 4);

    if (ws_size < off) {
        // workspace too small: distinguishable failure signature (out = 0)
        hipMemsetAsync(d_out, 0, (size_t)out_size * 4, stream);
        return;
    }

    hipMemsetAsync(counts, 0, NEXP * 4, stream);

    gating_kernel<<<1024, 256, 0, stream>>>(x, Wg, bg, xb, top_idx, top_w, counts);
    scan_kernel<<<1, 64, 0, stream>>>(counts, offsets, tmap_e, tmap_rt, ntiles, cursors);
    scatter_kernel<<<NTOK / 256, 256, 0, stream>>>(top_idx, top_w, offsets, cursors,
                                                   slot_tok, slot_w, pos);
    transpose_cvt<<<dim3(FDIM / 64, DDIM / 64, NEXP), 256, 0, stream>>>(W1, w1t, DDIM, FDIM);
    transpose_cvt<<<dim3(DDIM / 64, FDIM / 64, NEXP), 256, 0, stream>>>(W2, w2t, FDIM, DDIM);

    moe_gemm<DDIM, FDIM, true><<<dim3(FDIM / 128, MAXTILES), 512, 0, stream>>>(
        xb, w1t, b1, Hg, slot_tok, offsets, tmap_e, tmap_rt, ntiles);
    moe_gemm<FDIM, DDIM, false><<<dim3(DDIM / 128, MAXTILES), 512, 0, stream>>>(
        Hg, w2t, b2, Yg, slot_tok, offsets, tmap_e, tmap_rt, ntiles);

    combine_kernel<<<(NTOK * DDIM / 8) / 256, 256, 0, stream>>>(Yg, pos, slot_w, out);
}